// Round 1
// baseline (190.318 us; speedup 1.0000x reference)
//
#include <hip/hip_runtime.h>

#define B_SZ 8
#define N_SZ 1024
#define F_IN 128
#define C_DIM 128
#define E_FEAT 64
#define H_SZ 4
#define E_NUM 32768
#define NEG_SLOPE 0.2f

// ---------------------------------------------------------------------------
// Workspace layout (floats unless noted):
//  m_src   [128*4]      folded W_lin @ a_src
//  m_dst   [128*4]      folded W_lin @ a_dst
//  m_edge  [128*4]      folded W_edge @ a_edge
//  as_     [B*N*4]      src @ m_src
//  ad_     [B*N*4]      src @ m_dst
//  sw_     [B*N*4]      src @ m_edge
//  cnt     [1024] int   edges per source node
//  excl    [1024] int   exclusive prefix (CSR offsets)
//  cursor  [1024] int   fill cursors
//  ebuf    [E] int      dst node id per bucketed edge
// Total ~531 KB.
// ---------------------------------------------------------------------------

__global__ __launch_bounds__(256) void fold_mats(
    const float* __restrict__ W_lin, const float* __restrict__ a_src,
    const float* __restrict__ a_dst, const float* __restrict__ W_edge,
    const float* __restrict__ a_edge,
    float* __restrict__ m_src, float* __restrict__ m_dst,
    float* __restrict__ m_edge) {
  int idx = blockIdx.x * blockDim.x + threadIdx.x;
  if (idx >= F_IN * H_SZ) return;
  int f = idx >> 2, h = idx & 3;
  float accs = 0.f, accd = 0.f;
  for (int c = 0; c < C_DIM; ++c) {
    float w = W_lin[f * C_DIM + c];
    accs += w * a_src[c * H_SZ + h];
    accd += w * a_dst[c * H_SZ + h];
  }
  float acce = 0.f;
  for (int d = 0; d < E_FEAT; ++d)
    acce += W_edge[f * E_FEAT + d] * a_edge[d * H_SZ + h];
  m_src[idx] = accs; m_dst[idx] = accd; m_edge[idx] = acce;
}

__global__ __launch_bounds__(256) void node_vecs(
    const float* __restrict__ src, const float* __restrict__ m_src,
    const float* __restrict__ m_dst, const float* __restrict__ m_edge,
    float* __restrict__ as_, float* __restrict__ ad_, float* __restrict__ sw_) {
  int tid = blockIdx.x * blockDim.x + threadIdx.x;  // B*N*H threads
  int h = tid & 3;
  int bn = tid >> 2;
  const float* row = src + (size_t)bn * F_IN;
  float a = 0.f, d = 0.f, e = 0.f;
  for (int f = 0; f < F_IN; ++f) {
    float s = row[f];
    a += s * m_src[f * H_SZ + h];
    d += s * m_dst[f * H_SZ + h];
    e += s * m_edge[f * H_SZ + h];
  }
  as_[tid] = a; ad_[tid] = d; sw_[tid] = e;
}

__global__ __launch_bounds__(256) void count_edges(
    const int* __restrict__ ei, int* __restrict__ cnt) {
  int e = blockIdx.x * blockDim.x + threadIdx.x;
  if (e < E_NUM) atomicAdd(&cnt[ei[e]], 1);
}

__global__ __launch_bounds__(1024) void scan_counts(
    const int* __restrict__ cnt, int* __restrict__ excl,
    int* __restrict__ cursor) {
  __shared__ int s[N_SZ];
  int t = threadIdx.x;
  int v0 = cnt[t];
  s[t] = v0;
  __syncthreads();
  for (int d = 1; d < N_SZ; d <<= 1) {
    int v = (t >= d) ? s[t - d] : 0;
    __syncthreads();
    s[t] += v;
    __syncthreads();
  }
  int ex = s[t] - v0;
  excl[t] = ex;
  cursor[t] = ex;
}

__global__ __launch_bounds__(256) void fill_edges(
    const int* __restrict__ ei, int* __restrict__ cursor,
    int* __restrict__ ebuf) {
  int e = blockIdx.x * blockDim.x + threadIdx.x;
  if (e >= E_NUM) return;
  int i = ei[e];
  int j = ei[E_NUM + e];
  int pos = atomicAdd(&cursor[i], 1);
  ebuf[pos] = j;
}

// One block per (b, i) output row: N*H = 4096 floats = one 16 KiB LDS row.
__global__ __launch_bounds__(256) void attn_main(
    const float* __restrict__ as_, const float* __restrict__ ad_,
    const float* __restrict__ sw_, const int* __restrict__ cnt,
    const int* __restrict__ excl, const int* __restrict__ ebuf,
    float* __restrict__ out) {
  __shared__ float row[N_SZ * H_SZ];
  int i = blockIdx.x, b = blockIdx.y, t = threadIdx.x;

  float4* row4 = (float4*)row;
  for (int k = t; k < N_SZ; k += 256) row4[k] = make_float4(0.f, 0.f, 0.f, 0.f);

  const float4* sw4 = (const float4*)sw_;
  float4 swi = sw4[b * N_SZ + i];
  float4 asi = ((const float4*)as_)[b * N_SZ + i];
  __syncthreads();

  int off = excl[i], c = cnt[i];
  for (int k = t; k < c; k += 256) {
    int j = ebuf[off + k];
    float4 swj = sw4[b * N_SZ + j];
    atomicAdd(&row[j * 4 + 0], swi.x - swj.x);
    atomicAdd(&row[j * 4 + 1], swi.y - swj.y);
    atomicAdd(&row[j * 4 + 2], swi.z - swj.z);
    atomicAdd(&row[j * 4 + 3], swi.w - swj.w);
  }
  __syncthreads();

  const float4* ad4 = (const float4*)ad_;
  float4* out4 = (float4*)out + (size_t)(b * N_SZ + i) * N_SZ;
#pragma unroll
  for (int r = 0; r < 4; ++r) {
    int j = r * 256 + t;
    float4 adj = ad4[b * N_SZ + j];
    float4 rv = row4[j];
    float v0 = asi.x + adj.x + rv.x;
    float v1 = asi.y + adj.y + rv.y;
    float v2 = asi.z + adj.z + rv.z;
    float v3 = asi.w + adj.w + rv.w;
    v0 = v0 > 0.f ? v0 : v0 * NEG_SLOPE;
    v1 = v1 > 0.f ? v1 : v1 * NEG_SLOPE;
    v2 = v2 > 0.f ? v2 : v2 * NEG_SLOPE;
    v3 = v3 > 0.f ? v3 : v3 * NEG_SLOPE;
    float m = fmaxf(fmaxf(v0, v1), fmaxf(v2, v3));
    float e0 = __expf(v0 - m);
    float e1 = __expf(v1 - m);
    float e2 = __expf(v2 - m);
    float e3 = __expf(v3 - m);
    float inv = 1.f / (e0 + e1 + e2 + e3);
    out4[j] = make_float4(e0 * inv, e1 * inv, e2 * inv, e3 * inv);
  }
}

extern "C" void kernel_launch(void* const* d_in, const int* in_sizes, int n_in,
                              void* d_out, int out_size, void* d_ws,
                              size_t ws_size, hipStream_t stream) {
  const float* src    = (const float*)d_in[0];
  const int*   ei     = (const int*)d_in[1];
  const float* W_lin  = (const float*)d_in[2];
  const float* a_src  = (const float*)d_in[3];
  const float* a_dst  = (const float*)d_in[4];
  const float* W_edge = (const float*)d_in[5];
  const float* a_edge = (const float*)d_in[6];
  float* out = (float*)d_out;

  float* ws     = (float*)d_ws;
  float* m_src  = ws;
  float* m_dst  = ws + 512;
  float* m_edge = ws + 1024;
  float* as_    = ws + 1536;
  float* ad_    = as_ + B_SZ * N_SZ * H_SZ;
  float* sw_    = ad_ + B_SZ * N_SZ * H_SZ;
  int*   cnt    = (int*)(sw_ + B_SZ * N_SZ * H_SZ);
  int*   excl   = cnt + N_SZ;
  int*   cursor = excl + N_SZ;
  int*   ebuf   = cursor + N_SZ;

  hipMemsetAsync(cnt, 0, N_SZ * sizeof(int), stream);
  count_edges<<<E_NUM / 256, 256, 0, stream>>>(ei, cnt);
  scan_counts<<<1, 1024, 0, stream>>>(cnt, excl, cursor);
  fill_edges<<<E_NUM / 256, 256, 0, stream>>>(ei, cursor, ebuf);
  fold_mats<<<2, 256, 0, stream>>>(W_lin, a_src, a_dst, W_edge, a_edge,
                                   m_src, m_dst, m_edge);
  node_vecs<<<B_SZ * N_SZ * H_SZ / 256, 256, 0, stream>>>(
      src, m_src, m_dst, m_edge, as_, ad_, sw_);
  attn_main<<<dim3(N_SZ, B_SZ), 256, 0, stream>>>(as_, ad_, sw_, cnt, excl,
                                                  ebuf, out);
}